// Round 8
// baseline (140.336 us; speedup 1.0000x reference)
//
#include <hip/hip_runtime.h>

// Affine-IFS scan, decomposed v3. 512 blocks x 512 thr (8 waves x 64-step
// chunks, 64 points/block) = 2 blocks/CU so one block's load/compose overlaps
// the other's store-heavy replay (R7 had 1 block/CU -> serialized phases).
// Codes packed as nibbles in 8 VGPRs/lane; compose pair-idx = packed byte,
// replay idx = packed nibble, all compile-time extracts (no scratch).

#define B_PTS 16384
#define T_STEPS 512
#define N_TR 16
#define PTS_PER_BLK 64
#define WAVES 8
#define L_CHUNK 64   // T_STEPS / WAVES
#define THREADS 512
#define NPAIR 256

__global__ __launch_bounds__(THREADS, 4)   // 4 waves/EU -> 2 blocks/CU
void ifs_scan_v3(const float* __restrict__ init_pts,
                 const float* __restrict__ weights,
                 const float* __restrict__ biases,
                 const float* __restrict__ opac,
                 const int*   __restrict__ code,
                 float*       __restrict__ out)
{
    __shared__ float4 tabA[N_TR];                 // w00,w01,w10,w11
    __shared__ float4 tabB[N_TR];                 // bx,by,op,0
    __shared__ float4 pairA[NPAIR];               // A_j*A_i
    __shared__ float2 pairB[NPAIR];               // A_j*b_i + b_j
    __shared__ float4 mapsA[WAVES][PTS_PER_BLK];  // chunk map M
    __shared__ float2 mapsB[WAVES][PTS_PER_BLK];  // chunk map v
    // LDS ~18.7 KB/block -> 2 blocks fit easily

    const int tid  = threadIdx.x;
    const int lane = tid & 63;
    const int wv   = tid >> 6;
    const int base = blockIdx.x * PTS_PER_BLK;
    const int b    = base + lane;
    const int t0   = wv * L_CHUNK;

    // ---- load this wave's 64 chunk codes, pack 8 nibbles/dword ----
    unsigned nib[8];
    #pragma unroll
    for (int j = 0; j < 8; ++j) {
        unsigned acc = 0;
        #pragma unroll
        for (int k = 0; k < 8; ++k)
            acc |= (unsigned)code[(size_t)(t0 + 8*j + k) * B_PTS + b] << (4*k);
        nib[j] = acc;
    }

    // ---- build tables (once per block, from L2-resident globals) ----
    if (tid < N_TR) {
        tabA[tid] = make_float4(weights[tid*4+0], weights[tid*4+1],
                                weights[tid*4+2], weights[tid*4+3]);
        tabB[tid] = make_float4(biases[tid*2+0], biases[tid*2+1], opac[tid], 0.f);
    }
    if (tid >= 64 && tid < 64 + NPAIR) {          // waves 1..4 build pair table
        const int n = tid - 64;
        const int i = n & 15, j = n >> 4;         // apply i then j
        const float ai = weights[i*4+0], bi = weights[i*4+1];
        const float ci = weights[i*4+2], di = weights[i*4+3];
        const float aj = weights[j*4+0], bj = weights[j*4+1];
        const float cj = weights[j*4+2], dj = weights[j*4+3];
        const float bxi = biases[i*2+0], byi = biases[i*2+1];
        const float bxj = biases[j*2+0], byj = biases[j*2+1];
        pairA[n] = make_float4(aj*ai + bj*ci, aj*bi + bj*di,
                               cj*ai + dj*ci, cj*bi + dj*di);
        pairB[n] = make_float2(aj*bxi + bj*byi + bxj,
                               cj*bxi + dj*byi + byj);
    }
    __syncthreads();

    // ---- compose chunk map: 32 pair-steps, pidx = packed byte ----
    float m00 = 1.f, m01 = 0.f, m10 = 0.f, m11 = 1.f, vx = 0.f, vy = 0.f;
    #pragma unroll
    for (int j = 0; j < 8; ++j) {
        const unsigned w = nib[j];
        #pragma unroll
        for (int kk = 0; kk < 4; ++kk) {
            const int pidx = (w >> (8*kk)) & 255;   // low nibble applied first
            const float4 P = pairA[pidx];
            const float2 V = pairB[pidx];
            const float n00 = P.x * m00 + P.y * m10;
            const float n01 = P.x * m01 + P.y * m11;
            const float n10 = P.z * m00 + P.w * m10;
            const float n11 = P.z * m01 + P.w * m11;
            const float nvx = P.x * vx + P.y * vy + V.x;
            const float nvy = P.z * vx + P.w * vy + V.y;
            m00 = n00; m01 = n01; m10 = n10; m11 = n11; vx = nvx; vy = nvy;
        }
    }
    mapsA[wv][lane] = make_float4(m00, m01, m10, m11);
    mapsB[wv][lane] = make_float2(vx, vy);
    __syncthreads();

    // ---- prefix: apply chunk maps [0..wv) to init point ----
    const float2 p0 = *reinterpret_cast<const float2*>(&init_pts[(size_t)b * 2]);
    float px = p0.x, py = p0.y;
    for (int q = 0; q < wv; ++q) {      // wave-uniform trip count
        const float4 M = mapsA[q][lane];
        const float2 V = mapsB[q][lane];
        const float nx = M.x * px + M.y * py + V.x;
        const float ny = M.z * px + M.w * py + V.y;
        px = nx; py = ny;
    }

    // ---- replay chunk from packed nibbles, write output ----
    float* op = out + (size_t)((size_t)t0 * B_PTS + b) * 3;
    #pragma unroll
    for (int j = 0; j < 8; ++j) {
        const unsigned w = nib[j];
        #pragma unroll
        for (int k = 0; k < 8; ++k) {
            const int idx   = (w >> (4*k)) & 15;
            const float4 A  = tabA[idx];
            const float4 Bv = tabB[idx];
            const float nx = fmaf(A.x, px, fmaf(A.y, py, Bv.x));
            const float ny = fmaf(A.z, px, fmaf(A.w, py, Bv.y));
            px = nx; py = ny;
            op[0] = fmaf(px, 0.5f, 0.5f);
            op[1] = fmaf(py, 0.5f, 0.5f);
            op[2] = Bv.z;
            op += (size_t)B_PTS * 3;
        }
    }
}

extern "C" void kernel_launch(void* const* d_in, const int* in_sizes, int n_in,
                              void* d_out, int out_size, void* d_ws, size_t ws_size,
                              hipStream_t stream) {
    const float* init_pts = (const float*)d_in[0];
    const float* weights  = (const float*)d_in[1];
    const float* biases   = (const float*)d_in[2];
    const float* opac     = (const float*)d_in[3];
    const int*   code     = (const int*)d_in[4];
    float*       out      = (float*)d_out;

    ifs_scan_v3<<<B_PTS / PTS_PER_BLK, THREADS, 0, stream>>>(
        init_pts, weights, biases, opac, code, out);
}